// Round 5
// baseline (9481.251 us; speedup 1.0000x reference)
//
#include <hip/hip_runtime.h>
#include <cstddef>

// LSTM: N=64, T=512, D=512, H=512.
// gates[t] = [x_t | h_{t-1}] @ [Wx; Wh] + b  (K=1024, fp16 MFMA, fp32 accum)
// Persistent scan: 128 WGs x 256 thr, each WG owns 4 hidden units (16 gate
// cols), weights LDS-resident (fragment-linear, conflict-free).
// Sync: h exchanged as self-tagged u32 words ((t_tag<<16)|fp16) in a
// ping-pong buffer; stores fire-and-forget (agent-scope atomic store);
// discovery via per-WAVE-slice flag arrays; readers tag-verify and retry.
// ALL h loads are compiler-tracked __hip_atomic_load (no inline asm at all,
// so every register use of a load result gets a compiler-correct waitcnt).

typedef _Float16 half8 __attribute__((ext_vector_type(8)));
typedef float f32x4 __attribute__((ext_vector_type(4)));
typedef unsigned u32x4 __attribute__((ext_vector_type(4)));

#define NBATCH 64
#define TSTEPS 512
#define DIN    512
#define HID    512
#define NCOL   2048
#define SCAN_WGS 128
#define HSLOT  (NBATCH * HID)   // u32 words per ping-pong slot

__device__ __forceinline__ float fast_sigmoid(float x) {
  return 1.0f / (1.0f + __expf(-x));
}
__device__ __forceinline__ float fast_tanh(float x) {
  return 1.0f - 2.0f / (__expf(2.0f * x) + 1.0f);
}

// one-time per launch: x -> fp16; tagged h0 into slot 0; sentinel slot 1;
// reset 512 per-wave flags
__global__ void lstm_prep(const float* __restrict__ x, const float* __restrict__ h0,
                          _Float16* __restrict__ xb, unsigned* __restrict__ thx,
                          unsigned* __restrict__ flags)
{
  size_t gid = (size_t)blockIdx.x * blockDim.x + threadIdx.x;
  size_t stride = (size_t)gridDim.x * blockDim.x;
  const size_t NX = (size_t)NBATCH * TSTEPS * DIN;
  for (size_t i = gid * 4; i < NX; i += stride * 4) {
    float4 v = *(const float4*)(x + i);
    xb[i + 0] = (_Float16)v.x;
    xb[i + 1] = (_Float16)v.y;
    xb[i + 2] = (_Float16)v.z;
    xb[i + 3] = (_Float16)v.w;
  }
  for (size_t i = gid; i < (size_t)HSLOT; i += stride) {
    _Float16 hv = (_Float16)h0[i];
    thx[i] = (unsigned)__builtin_bit_cast(unsigned short, hv);  // tag 0
    thx[HSLOT + i] = 0xFFFFFFFFu;                               // sentinel
  }
  if (gid < 4 * SCAN_WGS) flags[gid] = 0u;
}

__global__ __launch_bounds__(256, 1) void lstm_scan(
    const _Float16* __restrict__ xb,   // [N][T][D] fp16
    const float* __restrict__ Wx,      // [D][4H]
    const float* __restrict__ Wh,      // [H][4H]
    const float* __restrict__ bias,    // [4H]
    unsigned* __restrict__ thx,        // [2][N][H] tagged u32 ping-pong
    float* __restrict__ out,           // [N][T][H] fp32
    unsigned* __restrict__ flags)      // [4][128] per-wave-slice step counters
{
  // fragment-linear weights: WF[ks][lane] = 16B B-fragment for K-slice ks
  __shared__ half8 WxF[16][64];        // 16 KB
  __shared__ half8 WhF[16][64];        // 16 KB

  const int wg   = blockIdx.x;         // owns hidden units wg*4..wg*4+3
  const int tid  = threadIdx.x;
  const int lane = tid & 63;
  const int wave = tid >> 6;           // m-slice: batch rows wave*16..+15

  // ---- one-time: stage weight slices fp32->fp16 into LDS (fragment order)
  {
    const int gate = tid & 3;
    const int k0   = tid >> 2;         // 0..63
    _Float16* wx = (_Float16*)WxF;
    _Float16* wh = (_Float16*)WhF;
    for (int pass = 0; pass < 8; ++pass) {
      int k = k0 + pass * 64;
      float4 vx = *(const float4*)(Wx + (size_t)k * NCOL + gate * 512 + wg * 4);
      float4 vh = *(const float4*)(Wh + (size_t)k * NCOL + gate * 512 + wg * 4);
      int base = (k >> 5) * 512 + (((k >> 3) & 3) * 16 + gate * 4) * 8 + (k & 7);
      wx[base + 0 * 8] = (_Float16)vx.x;
      wx[base + 1 * 8] = (_Float16)vx.y;
      wx[base + 2 * 8] = (_Float16)vx.z;
      wx[base + 3 * 8] = (_Float16)vx.w;
      wh[base + 0 * 8] = (_Float16)vh.x;
      wh[base + 1 * 8] = (_Float16)vh.y;
      wh[base + 2 * 8] = (_Float16)vh.z;
      wh[base + 3 * 8] = (_Float16)vh.w;
    }
  }
  __syncthreads();                     // the ONLY workgroup barrier

  // MFMA 16x16x32 fragment indices (A: row=lane&15, k=(lane>>4)*8+j;
  //  D: col=lane&15, row=(lane>>4)*4+j)
  const int fr = lane & 15;
  const int q  = lane >> 4;
  const int fk = q * 8;
  const int mrow = wave * 16 + fr;     // batch row of this lane's A-fragment

  // per-lane bias for gate column fr: gate g=fr>>2, hidden hj=fr&3
  const float bias_fr = bias[(fr >> 2) * 512 + wg * 4 + (fr & 3)];

  // writer identity: lane publishes cell (nw, colw), j_w = fr>>2
  const int jw   = fr >> 2;
  const int nw   = wave * 16 + q * 4 + jw;
  const int colw = wg * 4 + (fr & 3);

  // cell state for rows q*4+j (j=0..3), hidden unit fr&3 (replicated over g)
  float c0 = 0.f, c1 = 0.f, c2 = 0.f, c3 = 0.f;

  // preload x fragments for t=0
  half8 xa[16];
#pragma unroll
  for (int ks = 0; ks < 16; ++ks)
    xa[ks] = *(const half8*)(xb + ((size_t)mrow * TSTEPS + 0) * DIN + ks * 32 + fk);

  const unsigned long long* pollbase =
      (const unsigned long long*)(flags + wave * SCAN_WGS);

#define LOAD_HW()                                                             \
  _Pragma("unroll")                                                           \
  for (int ks = 0; ks < 16; ++ks) {                                           \
    _Pragma("unroll")                                                         \
    for (int e = 0; e < 8; ++e)                                               \
      hw[ks][e] = __hip_atomic_load(hbase + ks * 32 + e,                      \
                                    __ATOMIC_RELAXED, __HIP_MEMORY_SCOPE_AGENT); \
  }

  for (int t = 0; t < TSTEPS; ++t) {
    // ---- discovery: wave-slice barrier (flags >= t). t=0 trivially ready.
    if (t) {
      for (;;) {
        unsigned long long v = __hip_atomic_load(
            pollbase + lane, __ATOMIC_RELAXED, __HIP_MEMORY_SCOPE_AGENT);
        bool pok = ((unsigned)v >= (unsigned)t) &&
                   ((unsigned)(v >> 32) >= (unsigned)t);
        if (__all(pok)) break;
        __builtin_amdgcn_s_sleep(1);
      }
    }

    // ---- issue tagged-h loads (compiler-tracked; overlap x-MFMA) ----
    const unsigned* hbase = thx + (size_t)(t & 1) * HSLOT + (size_t)mrow * HID + fk;
    unsigned hw[16][8];
    LOAD_HW()

    // ---- x-MFMA phase (independent of h loads) ----
    f32x4 a0 = {0.f, 0.f, 0.f, 0.f};
    f32x4 a1 = {0.f, 0.f, 0.f, 0.f};
    f32x4 a2 = {0.f, 0.f, 0.f, 0.f};
    f32x4 a3 = {0.f, 0.f, 0.f, 0.f};
#pragma unroll
    for (int ks = 0; ks < 16; ks += 4) {
      a0 = __builtin_amdgcn_mfma_f32_16x16x32_f16(xa[ks],     WxF[ks][lane],     a0, 0, 0, 0);
      a1 = __builtin_amdgcn_mfma_f32_16x16x32_f16(xa[ks + 1], WxF[ks + 1][lane], a1, 0, 0, 0);
      a2 = __builtin_amdgcn_mfma_f32_16x16x32_f16(xa[ks + 2], WxF[ks + 2][lane], a2, 0, 0, 0);
      a3 = __builtin_amdgcn_mfma_f32_16x16x32_f16(xa[ks + 3], WxF[ks + 3][lane], a3, 0, 0, 0);
    }

    // ---- tag-verify + pack; retry (rare) until all tags == t ----
    half8 ha[16];
    const unsigned tagt = (unsigned)t;
    for (;;) {
      bool ok = true;
#pragma unroll
      for (int ks = 0; ks < 16; ++ks) {
        unsigned w0 = hw[ks][0], w1 = hw[ks][1], w2 = hw[ks][2], w3 = hw[ks][3];
        unsigned w4 = hw[ks][4], w5 = hw[ks][5], w6 = hw[ks][6], w7 = hw[ks][7];
        ok &= ((w0 >> 16) == tagt) & ((w1 >> 16) == tagt) &
              ((w2 >> 16) == tagt) & ((w3 >> 16) == tagt) &
              ((w4 >> 16) == tagt) & ((w5 >> 16) == tagt) &
              ((w6 >> 16) == tagt) & ((w7 >> 16) == tagt);
        u32x4 dv = {(w0 & 0xffffu) | (w1 << 16),
                    (w2 & 0xffffu) | (w3 << 16),
                    (w4 & 0xffffu) | (w5 << 16),
                    (w6 & 0xffffu) | (w7 << 16)};
        ha[ks] = __builtin_bit_cast(half8, dv);
      }
      if (__all(ok)) break;
      __builtin_amdgcn_s_sleep(1);
      LOAD_HW()
    }

    // ---- h-MFMA phase ----
#pragma unroll
    for (int ks = 0; ks < 16; ks += 4) {
      a0 = __builtin_amdgcn_mfma_f32_16x16x32_f16(ha[ks],     WhF[ks][lane],     a0, 0, 0, 0);
      a1 = __builtin_amdgcn_mfma_f32_16x16x32_f16(ha[ks + 1], WhF[ks + 1][lane], a1, 0, 0, 0);
      a2 = __builtin_amdgcn_mfma_f32_16x16x32_f16(ha[ks + 2], WhF[ks + 2][lane], a2, 0, 0, 0);
      a3 = __builtin_amdgcn_mfma_f32_16x16x32_f16(ha[ks + 3], WhF[ks + 3][lane], a3, 0, 0, 0);
    }
    f32x4 acc = (a0 + a1) + (a2 + a3);

    // ---- in-register LSTM cell (gates exchanged via shfl_xor 4/8) ----
    float h0v, h1v, h2v, h3v;
#define LSTM_CELL(J, CJ, HJ)                                                  \
    {                                                                         \
      float av = acc[J] + bias_fr;                                            \
      float v4 = __shfl_xor(av, 4);                                           \
      float alo = (fr & 4) ? v4 : av;                                         \
      float ahi = (fr & 4) ? av : v4;                                         \
      float blo = __shfl_xor(alo, 8);                                         \
      float bhi = __shfl_xor(ahi, 8);                                         \
      float iv = (fr & 8) ? blo : alo;   /* gate 0: i */                      \
      float fv = (fr & 8) ? bhi : ahi;   /* gate 1: f */                      \
      float ov = (fr & 8) ? alo : blo;   /* gate 2: o */                      \
      float gv = (fr & 8) ? ahi : bhi;   /* gate 3: g */                      \
      float ig = fast_sigmoid(iv);                                            \
      float fg = fast_sigmoid(fv);                                            \
      float og = fast_sigmoid(ov);                                            \
      float gg = fast_tanh(gv);                                               \
      CJ = fg * CJ + ig * gg;                                                 \
      HJ = og * fast_tanh(CJ);                                                \
    }
    LSTM_CELL(0, c0, h0v)
    LSTM_CELL(1, c1, h1v)
    LSTM_CELL(2, c2, h2v)
    LSTM_CELL(3, c3, h3v)
#undef LSTM_CELL

    // writer value: j == jw (static-select, keeps arrays out of scratch)
    float hsel = (jw == 0) ? h0v : (jw == 1) ? h1v : (jw == 2) ? h2v : h3v;

    // ---- publish: tagged h (fire-and-forget), flag, out ----
    {
      _Float16 h16 = (_Float16)hsel;
      unsigned packed = ((unsigned)(t + 1) << 16) |
                        (unsigned)__builtin_bit_cast(unsigned short, h16);
      unsigned* hdst = thx + (size_t)((t + 1) & 1) * HSLOT + (size_t)nw * HID + colw;
      __hip_atomic_store(hdst, packed, __ATOMIC_RELAXED, __HIP_MEMORY_SCOPE_AGENT);
    }
    if (lane == 0)
      __hip_atomic_store(&flags[wave * SCAN_WGS + wg], (unsigned)(t + 1),
                         __ATOMIC_RELAXED, __HIP_MEMORY_SCOPE_AGENT);
    out[((size_t)nw * TSTEPS + t) * HID + colw] = hsel;

    // ---- prefetch x for t+1 (lands during next poll window) ----
    if (t + 1 < TSTEPS) {
#pragma unroll
      for (int ks = 0; ks < 16; ++ks)
        xa[ks] = *(const half8*)(xb + ((size_t)mrow * TSTEPS + (t + 1)) * DIN + ks * 32 + fk);
    }
  }
#undef LOAD_HW
}

extern "C" void kernel_launch(void* const* d_in, const int* in_sizes, int n_in,
                              void* d_out, int out_size, void* d_ws, size_t ws_size,
                              hipStream_t stream) {
  const float* x  = (const float*)d_in[0];
  const float* h0 = (const float*)d_in[1];
  const float* Wx = (const float*)d_in[2];
  const float* Wh = (const float*)d_in[3];
  const float* b  = (const float*)d_in[4];
  float* out = (float*)d_out;

  char* ws = (char*)d_ws;
  _Float16* xb    = (_Float16*)ws;                           // 33,554,432 B
  unsigned* thx   = (unsigned*)(ws + 33554432);              //    262,144 B
  unsigned* flags = (unsigned*)(ws + 33554432 + 262144);     //      2,048 B

  lstm_prep<<<dim3(2048), dim3(256), 0, stream>>>(x, h0, xb, thx, flags);
  lstm_scan<<<dim3(SCAN_WGS), dim3(256), 0, stream>>>(xb, Wx, Wh, b, thx, out, flags);
}

// Round 6
// 4861.322 us; speedup vs baseline: 1.9503x; 1.9503x over previous
//
#include <hip/hip_runtime.h>
#include <cstddef>

// LSTM: N=64, T=512, D=512, H=512.
// gates[t] = [x_t | h_{t-1}] @ [Wx; Wh] + b  (K=1024, fp16 MFMA, fp32 accum)
// Persistent scan: 128 WGs x 256 thr, each WG owns 4 hidden units (16 gate
// cols), weights LDS-resident (fragment-linear, conflict-free).
// Sync (round-2-proven ordering, per-wave granularity):
//   producer: sc1 h stores -> s_waitcnt vmcnt(0) (asm, memory clobber only)
//             -> per-wave flag publish (monotonic, sc1)
//   consumer: poll 128 slice flags (64 lanes x u64) -> untagged fp16 h via
//             compiler-tracked 8B __hip_atomic_load (global_load_dwordx2 sc1)
// No __syncthreads in the loop; in-register shfl LSTM cell (validated r5).

typedef _Float16 half8 __attribute__((ext_vector_type(8)));
typedef float f32x4 __attribute__((ext_vector_type(4)));
typedef unsigned long long u64x2 __attribute__((ext_vector_type(2)));

#define NBATCH 64
#define TSTEPS 512
#define DIN    512
#define HID    512
#define NCOL   2048
#define SCAN_WGS 128
#define HSLOT  (NBATCH * HID)   // fp16 elements per ping-pong slot

__device__ __forceinline__ float fast_sigmoid(float x) {
  return 1.0f / (1.0f + __expf(-x));
}
__device__ __forceinline__ float fast_tanh(float x) {
  return 1.0f - 2.0f / (__expf(2.0f * x) + 1.0f);
}

// one-time per launch: x -> fp16; h0 -> slot 0; reset 512 per-wave flags
__global__ void lstm_prep(const float* __restrict__ x, const float* __restrict__ h0,
                          _Float16* __restrict__ xb, _Float16* __restrict__ hbuf,
                          unsigned* __restrict__ flags)
{
  size_t gid = (size_t)blockIdx.x * blockDim.x + threadIdx.x;
  size_t stride = (size_t)gridDim.x * blockDim.x;
  const size_t NX = (size_t)NBATCH * TSTEPS * DIN;
  for (size_t i = gid * 4; i < NX; i += stride * 4) {
    float4 v = *(const float4*)(x + i);
    xb[i + 0] = (_Float16)v.x;
    xb[i + 1] = (_Float16)v.y;
    xb[i + 2] = (_Float16)v.z;
    xb[i + 3] = (_Float16)v.w;
  }
  for (size_t i = gid; i < (size_t)HSLOT; i += stride)
    hbuf[i] = (_Float16)h0[i];
  if (gid < 4 * SCAN_WGS) flags[gid] = 0u;
}

__global__ __launch_bounds__(256, 1) void lstm_scan(
    const _Float16* __restrict__ xb,   // [N][T][D] fp16
    const float* __restrict__ Wx,      // [D][4H]
    const float* __restrict__ Wh,      // [H][4H]
    const float* __restrict__ bias,    // [4H]
    _Float16* __restrict__ hbuf,       // [2][N][H] fp16 ping-pong
    float* __restrict__ out,           // [N][T][H] fp32
    unsigned* __restrict__ flags)      // [4][128] per-wave-slice step counters
{
  // fragment-linear weights: WF[ks][lane] = 16B B-fragment for K-slice ks
  __shared__ half8 WxF[16][64];        // 16 KB
  __shared__ half8 WhF[16][64];        // 16 KB

  const int wg   = blockIdx.x;         // owns hidden units wg*4..wg*4+3
  const int tid  = threadIdx.x;
  const int lane = tid & 63;
  const int wave = tid >> 6;           // m-slice: batch rows wave*16..+15

  // ---- one-time: stage weight slices fp32->fp16 into LDS (fragment order)
  {
    const int gate = tid & 3;
    const int k0   = tid >> 2;         // 0..63
    _Float16* wx = (_Float16*)WxF;
    _Float16* wh = (_Float16*)WhF;
    for (int pass = 0; pass < 8; ++pass) {
      int k = k0 + pass * 64;
      float4 vx = *(const float4*)(Wx + (size_t)k * NCOL + gate * 512 + wg * 4);
      float4 vh = *(const float4*)(Wh + (size_t)k * NCOL + gate * 512 + wg * 4);
      int base = (k >> 5) * 512 + (((k >> 3) & 3) * 16 + gate * 4) * 8 + (k & 7);
      wx[base + 0 * 8] = (_Float16)vx.x;
      wx[base + 1 * 8] = (_Float16)vx.y;
      wx[base + 2 * 8] = (_Float16)vx.z;
      wx[base + 3 * 8] = (_Float16)vx.w;
      wh[base + 0 * 8] = (_Float16)vh.x;
      wh[base + 1 * 8] = (_Float16)vh.y;
      wh[base + 2 * 8] = (_Float16)vh.z;
      wh[base + 3 * 8] = (_Float16)vh.w;
    }
  }
  __syncthreads();                     // the ONLY workgroup barrier

  // MFMA 16x16x32 fragment indices (A: row=lane&15, k=(lane>>4)*8+j;
  //  D: col=lane&15, row=(lane>>4)*4+j)
  const int fr = lane & 15;
  const int q  = lane >> 4;
  const int fk = q * 8;
  const int mrow = wave * 16 + fr;     // batch row of this lane's A-fragment

  // per-lane bias for gate column fr: gate g=fr>>2, hidden hj=fr&3
  const float bias_fr = bias[(fr >> 2) * 512 + wg * 4 + (fr & 3)];

  // writer identity: lane publishes cell (nw, colw), j_w = fr>>2
  const int jw   = fr >> 2;
  const int nw   = wave * 16 + q * 4 + jw;
  const int colw = wg * 4 + (fr & 3);

  // cell state for rows q*4+j (j=0..3), hidden unit fr&3 (replicated over g)
  float c0 = 0.f, c1 = 0.f, c2 = 0.f, c3 = 0.f;

  // preload x fragments for t=0
  half8 xa[16];
#pragma unroll
  for (int ks = 0; ks < 16; ++ks)
    xa[ks] = *(const half8*)(xb + ((size_t)mrow * TSTEPS + 0) * DIN + ks * 32 + fk);

  const unsigned long long* pollbase =
      (const unsigned long long*)(flags + wave * SCAN_WGS);

  for (int t = 0; t < TSTEPS; ++t) {
    // ---- discovery: wave-slice barrier (flags >= t). t=0 trivially ready.
    if (t) {
      for (;;) {
        unsigned long long v = __hip_atomic_load(
            pollbase + lane, __ATOMIC_RELAXED, __HIP_MEMORY_SCOPE_AGENT);
        bool pok = ((unsigned)v >= (unsigned)t) &&
                   ((unsigned)(v >> 32) >= (unsigned)t);
        if (__all(pok)) break;
        __builtin_amdgcn_s_sleep(1);
      }
    }

    // ---- issue h loads: 16 frags x 2 u64 (compiler-tracked dwordx2 sc1) ----
    // frag ks bytes: row mrow, fp16 cols ks*32+q*8 .. +7  ->  u64 words
    // (hrow as u64*)[ks*8 + q*2] and [ks*8 + q*2 + 1]
    const unsigned long long* hrow = (const unsigned long long*)
        (hbuf + (size_t)(t & 1) * HSLOT + (size_t)mrow * HID);
    unsigned long long hl[16][2];
#pragma unroll
    for (int ks = 0; ks < 16; ++ks) {
      hl[ks][0] = __hip_atomic_load(hrow + ks * 8 + q * 2,
                                    __ATOMIC_RELAXED, __HIP_MEMORY_SCOPE_AGENT);
      hl[ks][1] = __hip_atomic_load(hrow + ks * 8 + q * 2 + 1,
                                    __ATOMIC_RELAXED, __HIP_MEMORY_SCOPE_AGENT);
    }

    // ---- x-MFMA phase (independent of h loads; overlaps their flight) ----
    f32x4 a0 = {0.f, 0.f, 0.f, 0.f};
    f32x4 a1 = {0.f, 0.f, 0.f, 0.f};
    f32x4 a2 = {0.f, 0.f, 0.f, 0.f};
    f32x4 a3 = {0.f, 0.f, 0.f, 0.f};
#pragma unroll
    for (int ks = 0; ks < 16; ks += 4) {
      a0 = __builtin_amdgcn_mfma_f32_16x16x32_f16(xa[ks],     WxF[ks][lane],     a0, 0, 0, 0);
      a1 = __builtin_amdgcn_mfma_f32_16x16x32_f16(xa[ks + 1], WxF[ks + 1][lane], a1, 0, 0, 0);
      a2 = __builtin_amdgcn_mfma_f32_16x16x32_f16(xa[ks + 2], WxF[ks + 2][lane], a2, 0, 0, 0);
      a3 = __builtin_amdgcn_mfma_f32_16x16x32_f16(xa[ks + 3], WxF[ks + 3][lane], a3, 0, 0, 0);
    }

    // ---- h-MFMA phase (compiler inserts counted waits on hl) ----
#pragma unroll
    for (int ks = 0; ks < 16; ks += 4) {
      u64x2 d0 = {hl[ks][0],     hl[ks][1]};
      u64x2 d1 = {hl[ks + 1][0], hl[ks + 1][1]};
      u64x2 d2 = {hl[ks + 2][0], hl[ks + 2][1]};
      u64x2 d3 = {hl[ks + 3][0], hl[ks + 3][1]};
      a0 = __builtin_amdgcn_mfma_f32_16x16x32_f16(__builtin_bit_cast(half8, d0), WhF[ks][lane],     a0, 0, 0, 0);
      a1 = __builtin_amdgcn_mfma_f32_16x16x32_f16(__builtin_bit_cast(half8, d1), WhF[ks + 1][lane], a1, 0, 0, 0);
      a2 = __builtin_amdgcn_mfma_f32_16x16x32_f16(__builtin_bit_cast(half8, d2), WhF[ks + 2][lane], a2, 0, 0, 0);
      a3 = __builtin_amdgcn_mfma_f32_16x16x32_f16(__builtin_bit_cast(half8, d3), WhF[ks + 3][lane], a3, 0, 0, 0);
    }
    f32x4 acc = (a0 + a1) + (a2 + a3);

    // ---- in-register LSTM cell (gates exchanged via shfl_xor 4/8) ----
    float h0v, h1v, h2v, h3v;
#define LSTM_CELL(J, CJ, HJ)                                                  \
    {                                                                         \
      float av = acc[J] + bias_fr;                                            \
      float v4 = __shfl_xor(av, 4);                                           \
      float alo = (fr & 4) ? v4 : av;                                         \
      float ahi = (fr & 4) ? av : v4;                                         \
      float blo = __shfl_xor(alo, 8);                                         \
      float bhi = __shfl_xor(ahi, 8);                                         \
      float iv = (fr & 8) ? blo : alo;   /* gate 0: i */                      \
      float fv = (fr & 8) ? bhi : ahi;   /* gate 1: f */                      \
      float ov = (fr & 8) ? alo : blo;   /* gate 2: o */                      \
      float gv = (fr & 8) ? ahi : bhi;   /* gate 3: g */                      \
      float ig = fast_sigmoid(iv);                                            \
      float fg = fast_sigmoid(fv);                                            \
      float og = fast_sigmoid(ov);                                            \
      float gg = fast_tanh(gv);                                               \
      CJ = fg * CJ + ig * gg;                                                 \
      HJ = og * fast_tanh(CJ);                                                \
    }
    LSTM_CELL(0, c0, h0v)
    LSTM_CELL(1, c1, h1v)
    LSTM_CELL(2, c2, h2v)
    LSTM_CELL(3, c3, h3v)
#undef LSTM_CELL

    // writer value: j == jw (static-select, keeps arrays out of scratch)
    float hsel = (jw == 0) ? h0v : (jw == 1) ? h1v : (jw == 2) ? h2v : h3v;

    // ---- publish h: pack fp16 pair with partner lane, sc1 u32 store ----
    {
      float hpart = __shfl_xor(hsel, 1);
      if ((fr & 1) == 0) {
        _Float16 lo = (_Float16)hsel, hi = (_Float16)hpart;
        unsigned packed = (unsigned)__builtin_bit_cast(unsigned short, lo) |
                          ((unsigned)__builtin_bit_cast(unsigned short, hi) << 16);
        unsigned* hdst = (unsigned*)(hbuf + (size_t)((t + 1) & 1) * HSLOT +
                                     (size_t)nw * HID + colw);
        __hip_atomic_store(hdst, packed, __ATOMIC_RELAXED, __HIP_MEMORY_SCOPE_AGENT);
      }
    }
    out[((size_t)nw * TSTEPS + t) * HID + colw] = hsel;

    // ---- ack: h stores at coherence point, then per-wave flag publish ----
    asm volatile("s_waitcnt vmcnt(0)" ::: "memory");
    if (lane == 0)
      __hip_atomic_store(&flags[wave * SCAN_WGS + wg], (unsigned)(t + 1),
                         __ATOMIC_RELAXED, __HIP_MEMORY_SCOPE_AGENT);

    // ---- prefetch x for t+1 (lands during next poll window) ----
    if (t + 1 < TSTEPS) {
#pragma unroll
      for (int ks = 0; ks < 16; ++ks)
        xa[ks] = *(const half8*)(xb + ((size_t)mrow * TSTEPS + (t + 1)) * DIN + ks * 32 + fk);
    }
  }
}

extern "C" void kernel_launch(void* const* d_in, const int* in_sizes, int n_in,
                              void* d_out, int out_size, void* d_ws, size_t ws_size,
                              hipStream_t stream) {
  const float* x  = (const float*)d_in[0];
  const float* h0 = (const float*)d_in[1];
  const float* Wx = (const float*)d_in[2];
  const float* Wh = (const float*)d_in[3];
  const float* b  = (const float*)d_in[4];
  float* out = (float*)d_out;

  char* ws = (char*)d_ws;
  _Float16* xb    = (_Float16*)ws;                           // 33,554,432 B
  _Float16* hbuf  = (_Float16*)(ws + 33554432);              //    262,144 B
  unsigned* flags = (unsigned*)(ws + 33554432 + 262144);     //      2,048 B

  lstm_prep<<<dim3(2048), dim3(256), 0, stream>>>(x, h0, xb, hbuf, flags);
  lstm_scan<<<dim3(SCAN_WGS), dim3(256), 0, stream>>>(xb, Wx, Wh, b, hbuf, out, flags);
}